// Round 2
// baseline (887.499 us; speedup 1.0000x reference)
//
#include <hip/hip_runtime.h>
#include <hip/hip_bf16.h>

typedef __attribute__((ext_vector_type(8))) short s8b;     // 8 bf16 (4 VGPRs)
typedef __attribute__((ext_vector_type(4))) float f32x4;   // MFMA accumulator
typedef __attribute__((ext_vector_type(4))) unsigned u32x4;

#define NND 50000
#define NED 800000
#define EPB 128     // edges per block
#define EPW 32      // edges per wave
#define SCH 200     // scan chunks
#define SCS 250     // chunk size: 200*250 = 50000

// workspace layout (bf16-element offsets for weights, byte offsets for f32)
#define WM1T_OFF 0         // [128][384] folded+transposed Wm1'
#define WM2T_OFF 49152     // [128][128]
#define WV1T_OFF 65536     // [128][128]
#define WV2T_OFF 81920     // [80][128]
#define WS1T_OFF 92160     // [128][256]
#define WS2T_OFF 124928    // [128][128]
#define BM1F_BYTE 282624   // 128 f32 (folded bias)
#define ACC_BYTE  283136   // f32 accumulators start (16B aligned)
#define ZACC_ELEMS (NND*48)
#define MACC_ELEMS (NND*128)
#define ACC_TOTAL (ZACC_ELEMS + MACC_ELEMS + NND)   // Zacc + macc + deg (zeroed)
// ints after acc: cursor[NND], perm[NED], part[256]
#define WS_MIN  (ACC_BYTE + (size_t)(ACC_TOTAL + NND + NED + 256)*4)
// optional staging: Z bf16 + per-node L1 partials Yd (f32, frag layout) + Ys (bf16, frag layout)
#define ZB_BYTE  ((WS_MIN + 15) & ~(size_t)15)
#define YD_BYTE  (ZB_BYTE + (size_t)NND*48*2)
#define YS_BYTE  (YD_BYTE + (size_t)NND*128*4)
#define WS_FULL  (YS_BYTE + (size_t)NND*128*2)

// accurate RNE cvt (prep only)
__device__ __forceinline__ short f2bs(float x){
    __hip_bfloat16 b = __float2bfloat16(x);
    return __builtin_bit_cast(short, b);
}
// fast cvt: round-half-up, 2 VALU ops (finite inputs only)
__device__ __forceinline__ short f2bs_fast(float x){
    unsigned u = __builtin_bit_cast(unsigned, x) + 0x8000u;
    return (short)(u >> 16);
}
// pack 2 floats -> 2 bf16 in one dword (lo=a, hi=b)
__device__ __forceinline__ unsigned pk2(float a, float b){
    unsigned ua = __builtin_bit_cast(unsigned, a) + 0x8000u;
    unsigned ub = __builtin_bit_cast(unsigned, b) + 0x8000u;
    return __builtin_amdgcn_perm(ub, ua, 0x07060302u);
}
__device__ __forceinline__ float bs2f(short s){
    unsigned u = ((unsigned)(unsigned short)s) << 16;
    return __builtin_bit_cast(float, u);
}
__device__ __forceinline__ float upk_lo(unsigned u){
    return __builtin_bit_cast(float, u << 16);
}
__device__ __forceinline__ float upk_hi(unsigned u){
    return __builtin_bit_cast(float, u & 0xffff0000u);
}
__device__ __forceinline__ float silu_f(float x){
    float e = __expf(-x);
    return x * __builtin_amdgcn_rcpf(1.0f + e);
}
// load 8 consecutive f32 (16B-aligned) -> bf16 fragment
__device__ __forceinline__ s8b load8f_bf(const float* p){
    f32x4 a = *(const f32x4*)p;
    f32x4 b = *(const f32x4*)(p + 4);
    u32x4 r;
    r[0] = pk2(a[0], a[1]); r[1] = pk2(a[2], a[3]);
    r[2] = pk2(b[0], b[1]); r[3] = pk2(b[2], b[3]);
    return __builtin_bit_cast(s8b, r);
}

#define MFMA16(a,b,c) __builtin_amdgcn_mfma_f32_16x16x32_bf16((a),(b),(c),0,0,0)
#define LDS_FENCE() asm volatile("s_waitcnt lgkmcnt(0)" ::: "memory")

// ---------------- zero / cvt ----------------
__global__ __launch_bounds__(256) void zero_kernel(float* __restrict__ p, int n)
{
    int i = blockIdx.x*256 + threadIdx.x;
    int stride = gridDim.x*256;
    for (; i < n; i += stride) p[i] = 0.0f;
}
__global__ __launch_bounds__(256) void cvt_kernel(const float* __restrict__ src,
                                                  short* __restrict__ dst, int n)
{
    int i = blockIdx.x*256 + threadIdx.x;
    int stride = gridDim.x*256;
    for (; i < n; i += stride) dst[i] = f2bs(src[i]);
}

// ---------------- weight prep ----------------
__global__ __launch_bounds__(256) void fold_kernel(
    const float* __restrict__ We, const float* __restrict__ be,
    const float* __restrict__ Wm1, const float* __restrict__ bm1,
    short* __restrict__ Wm1T, float* __restrict__ bm1f)
{
    int idx = blockIdx.x*256 + threadIdx.x;
    if (idx >= 128*384) return;
    int n = idx / 384, k = idx - n*384;
    float v;
    if (k < 356) v = Wm1[(size_t)k*128 + n];
    else if (k < 372) {
        int j = k - 356; float s = 0.f;
        for (int c = 0; c < 128; c++)
            s += We[j*128 + c] * Wm1[(size_t)(356+c)*128 + n];
        v = s;
    } else v = 0.f;
    Wm1T[(size_t)n*384 + k] = f2bs(v);
    if (k == 0) {
        float s = bm1[n];
        for (int c = 0; c < 128; c++)
            s += be[c] * Wm1[(size_t)(356+c)*128 + n];
        bm1f[n] = s;
    }
}

__global__ __launch_bounds__(256) void prep_kernel(
    const float* __restrict__ Wm2, const float* __restrict__ Wv1,
    const float* __restrict__ Wv2, const float* __restrict__ Ws1,
    const float* __restrict__ Ws2, short* __restrict__ wsb)
{
    int i = blockIdx.x*256 + threadIdx.x;
    if (i < 16384) { int k=i>>7, n=i&127; wsb[WM2T_OFF + n*128 + k] = f2bs(Wm2[i]); return; }
    i -= 16384;
    if (i < 16384) { int k=i>>7, n=i&127; wsb[WV1T_OFF + n*128 + k] = f2bs(Wv1[i]); return; }
    i -= 16384;
    if (i < 10240) { int k=i/80, n=i-k*80; wsb[WV2T_OFF + n*128 + k] = f2bs(Wv2[i]); return; }
    i -= 10240;
    if (i < 32768) { int k=i>>7, n=i&127; wsb[WS1T_OFF + n*256 + k] = f2bs(Ws1[i]); return; }
    i -= 32768;
    if (i < 16384) { int k=i>>7, n=i&127; wsb[WS2T_OFF + n*128 + k] = f2bs(Ws2[i]); return; }
}

// ---------------- per-node L1 partials ----------------
// Yd = h @ Wm1[h_i] (f32, fragment layout [node][c15*8+nt] <-> col nt*16+c15)
// Ys = h @ Wm1[h_j] (bf16, same layout) -- src-side gather traffic halved
__global__ __launch_bounds__(256) void y_kernel(
    const float* __restrict__ h, const short* __restrict__ Wm1T,
    float* __restrict__ Yd, short* __restrict__ Ysb)
{
    const int tid = threadIdx.x, lane = tid & 63, wave = tid >> 6;
    const int quad = lane >> 4, c15 = lane & 15;
    const int nbase = blockIdx.x * 64 + wave * 16;
    int ndA = nbase + c15; if (ndA >= NND) ndA = NND - 1;   // clamp; stores guarded
    const float* hA = h + (size_t)ndA*128 + quad*8;
    const f32x4 z4 = {0.f,0.f,0.f,0.f};
    f32x4 ad[8], as_[8];
    #pragma unroll
    for (int nt = 0; nt < 8; nt++) { ad[nt] = z4; as_[nt] = z4; }
    const short* Bd = Wm1T + (size_t)c15*384 + quad*8;      // k 0..127  (h_i / dst)
    const short* Bs = Bd + 128;                             // k 128..255 (h_j / src)
    #pragma unroll
    for (int ks = 0; ks < 4; ks++) {
        s8b a = load8f_bf(hA + ks*32);
        #pragma unroll
        for (int nt = 0; nt < 8; nt++) {
            s8b bd = *(const s8b*)(Bd + nt*(16*384) + ks*32);
            s8b bs = *(const s8b*)(Bs + nt*(16*384) + ks*32);
            ad[nt]  = MFMA16(a, bd, ad[nt]);
            as_[nt] = MFMA16(a, bs, as_[nt]);
        }
    }
    #pragma unroll
    for (int r = 0; r < 4; r++) {
        const int nd = nbase + quad*4 + r;
        if (nd < NND) {
            f32x4 w0 = {ad[0][r], ad[1][r], ad[2][r], ad[3][r]};
            f32x4 w1 = {ad[4][r], ad[5][r], ad[6][r], ad[7][r]};
            *(f32x4*)(Yd + (size_t)nd*128 + c15*8)     = w0;
            *(f32x4*)(Yd + (size_t)nd*128 + c15*8 + 4) = w1;
            s8b yv;
            #pragma unroll
            for (int nt = 0; nt < 8; nt++) yv[nt] = f2bs(as_[nt][r]);
            *(s8b*)(Ysb + (size_t)nd*128 + c15*8) = yv;
        }
    }
}

// ---------------- counting sort by dst ----------------
__global__ __launch_bounds__(256) void hist_kernel(const int* __restrict__ ei, int* __restrict__ deg)
{
    int e = blockIdx.x*256 + threadIdx.x;
    if (e < NED) atomicAdd(&deg[ei[NED + e]], 1);
}

__global__ __launch_bounds__(256) void scan1_kernel(const int* __restrict__ deg, int* __restrict__ part)
{
    __shared__ int red[256];
    int b = blockIdx.x, t = threadIdx.x;
    red[t] = (t < SCS) ? deg[b*SCS + t] : 0;
    __syncthreads();
    for (int s = 128; s > 0; s >>= 1) {
        if (t < s) red[t] += red[t+s];
        __syncthreads();
    }
    if (t == 0) part[b] = red[0];
}
// parallel exclusive scan of the SCH partial sums (was: 1 thread x 200 global round-trips)
__global__ __launch_bounds__(256) void scan2_kernel(int* __restrict__ part)
{
    __shared__ int buf[256];
    int t = threadIdx.x;
    int v = (t < SCH) ? part[t] : 0;
    buf[t] = v;
    __syncthreads();
    for (int s = 1; s < 256; s <<= 1) {
        int add = (t >= s) ? buf[t-s] : 0;
        __syncthreads();
        buf[t] += add;
        __syncthreads();
    }
    if (t < SCH) part[t] = buf[t] - v;   // exclusive
}
__global__ __launch_bounds__(256) void scan3_kernel(const int* __restrict__ deg,
                                                    const int* __restrict__ part,
                                                    int* __restrict__ cursor)
{
    __shared__ int buf[256];
    int b = blockIdx.x, t = threadIdx.x;
    int v = (t < SCS) ? deg[b*SCS + t] : 0;
    buf[t] = v;
    __syncthreads();
    for (int s = 1; s < 256; s <<= 1) {
        int add = (t >= s) ? buf[t-s] : 0;
        __syncthreads();
        buf[t] += add;
        __syncthreads();
    }
    if (t < SCS) cursor[b*SCS + t] = part[b] + buf[t] - v;   // exclusive
}

__global__ __launch_bounds__(256) void scatter_kernel(const int* __restrict__ ei,
                                                      int* __restrict__ cursor,
                                                      int* __restrict__ perm)
{
    int e = blockIdx.x*256 + threadIdx.x;
    if (e < NED) {
        int d = ei[NED + e];
        int p = atomicAdd(&cursor[d], 1);
        perm[p] = e;
    }
}

// ---------------- edge kernel ----------------
// 128 dst-sorted edges/block, 4 waves x 32 edges (2 MFMA A-tiles).
// Everything wave-private: NO __syncthreads, only lgkm fences.
// BF=1: Z read from bf16-staged copy; L1 h-part from per-node Y partials,
//       added at the MFMA epilogue (zero-init acc -> MFMA never blocks on the gather).
template<int BF>
__global__ __launch_bounds__(256, 4) void edge_kernel(
    const float* __restrict__ Z, const float* __restrict__ h,
    const short* __restrict__ Zb,
    const float* __restrict__ Ydf, const short* __restrict__ Ysb,
    const int* __restrict__ ei, const int* __restrict__ perm,
    const float* __restrict__ edf, const float* __restrict__ edv,
    const short* __restrict__ Wm1T, const float* __restrict__ bm1f,
    const short* __restrict__ Wm2T, const float* __restrict__ bm2,
    const short* __restrict__ Wv1T, const float* __restrict__ bv1,
    const short* __restrict__ Wv2T, const float* __restrict__ bv2,
    float* __restrict__ Zacc, float* __restrict__ macc)
{
    __shared__ __align__(16) short ssh[EPB*136];  // invar/edf -> act1 -> msg -> act3 -> Z+Zagg
    __shared__ int srcs[EPB], dsts[EPB];

    const int tid  = threadIdx.x;
    const int lane = tid & 63;
    const int wave = tid >> 6;
    const int wb   = wave * EPW;

    // bijective XCD-chunked swizzle (nwg % 8 != 0 -> m204 variant):
    // dst-sorted blocks get contiguous per-XCD ranges -> Yd/macc/Zacc L2 locality
    const int nwg = gridDim.x;
    const int qq = nwg >> 3, rr = nwg & 7;
    const int xcd = blockIdx.x & 7, bidx = blockIdx.x >> 3;
    const int bswz = (xcd < rr ? xcd*(qq+1) : rr*(qq+1) + (xcd-rr)*qq) + bidx;
    const int ebase = bswz * EPB;

    const int row = wb + (lane >> 1);
    const int sub = lane & 1;          // h-parity: this lane owns h = 2*sub, 2*sub+1

    // ---- Phase A: indices + Z_ij diffs (packed bf16 pairs) + invariants ----
    unsigned zp[15];    // [g=d*4+t] for t<4 ; zp[12+d] = edv pair
    {
        const int e = perm[ebase + row];
        const int s = ei[e], d = ei[NED + e];
        if (sub == 0) { srcs[row] = s; dsts[row] = d; }
        unsigned pA[6], pB[6], rc[6];
        if (BF) {
            const s8b zd0 = *(const s8b*)(Zb + (size_t)d*48 + sub*24);
            const s8b zd1 = *(const s8b*)(Zb + (size_t)d*48 + sub*24 + 8);
            const s8b zd2 = *(const s8b*)(Zb + (size_t)d*48 + sub*24 + 16);
            const s8b zs0 = *(const s8b*)(Zb + (size_t)s*48 + sub*24);
            const s8b zs1 = *(const s8b*)(Zb + (size_t)s*48 + sub*24 + 8);
            const s8b zs2 = *(const s8b*)(Zb + (size_t)s*48 + sub*24 + 16);
            u32x4 ud01 = __builtin_bit_cast(u32x4, zd0);
            u32x4 ud23 = __builtin_bit_cast(u32x4, zd1);
            u32x4 ud45 = __builtin_bit_cast(u32x4, zd2);
            u32x4 us01 = __builtin_bit_cast(u32x4, zs0);
            u32x4 us23 = __builtin_bit_cast(u32x4, zs1);
            u32x4 us45 = __builtin_bit_cast(u32x4, zs2);
            unsigned ud[12], us[12];
            #pragma unroll
            for (int j = 0; j < 4; j++) {
                ud[j] = ud01[j]; ud[4+j] = ud23[j]; ud[8+j] = ud45[j];
                us[j] = us01[j]; us[4+j] = us23[j]; us[8+j] = us45[j];
            }
            #pragma unroll
            for (int q = 0; q < 6; q++) {
                float l0 = upk_lo(ud[2*q])   - upk_lo(us[2*q]);
                float h0 = upk_hi(ud[2*q])   - upk_hi(us[2*q]);
                float l1 = upk_lo(ud[2*q+1]) - upk_lo(us[2*q+1]);
                float h1 = upk_hi(ud[2*q+1]) - upk_hi(us[2*q+1]);
                pA[q] = pk2(l0, h0);
                pB[q] = pk2(l1, h1);
            }
        } else {
            const float* Zs = Z + (size_t)s*48 + sub*24;
            const float* Zd = Z + (size_t)d*48 + sub*24;
            float dv[24];
            #pragma unroll
            for (int q = 0; q < 6; q++) {
                f32x4 a = *(const f32x4*)(Zd + q*4);
                f32x4 b = *(const f32x4*)(Zs + q*4);
                dv[q*4+0] = a[0]-b[0]; dv[q*4+1] = a[1]-b[1];
                dv[q*4+2] = a[2]-b[2]; dv[q*4+3] = a[3]-b[3];
            }
            #pragma unroll
            for (int q = 0; q < 6; q++) {
                pA[q] = pk2(dv[q*4+0], dv[q*4+1]);
                pB[q] = pk2(dv[q*4+2], dv[q*4+3]);
            }
        }
        #pragma unroll
        for (int q = 0; q < 6; q++)
            rc[q] = (unsigned)__shfl_xor((int)(sub ? pA[q] : pB[q]), 1);
        #pragma unroll
        for (int i = 0; i < 6; i++) zp[i]   = sub ? rc[i] : pA[i];
        #pragma unroll
        for (int i = 0; i < 6; i++) zp[6+i] = sub ? pB[i] : rc[i];
        float e0 = edv[(size_t)e*3+0], e1 = edv[(size_t)e*3+1], e2 = edv[(size_t)e*3+2];
        zp[12] = pk2(e0,e0); zp[13] = pk2(e1,e1); zp[14] = pk2(e2,e2);

        // invariants (register-local Gram, h-diagonal)
        float zt0[15], zt1[15];
        #pragma unroll
        for (int i = 0; i < 15; i++) { zt0[i] = upk_lo(zp[i]); zt1[i] = upk_hi(zp[i]); }
        const int PT[15] = {0,0,0,0,0,1,1,1,1,2,2,2,3,3,4};
        const int PR[15] = {0,1,2,3,4,1,2,3,4,2,3,4,3,4,4};
        float v0[15], v1[15];
        float ssql = 0.f;
        #pragma unroll
        for (int k = 0; k < 15; k++) {
            const int tt = PT[k], rr2 = PR[k];
            float a0 = 0.f, a1 = 0.f;
            #pragma unroll
            for (int d2 = 0; d2 < 3; d2++) {
                const int gt = (tt < 4) ? d2*4 + tt : 12 + d2;
                const int gr = (rr2 < 4) ? d2*4 + rr2 : 12 + d2;
                a0 += zt0[gt]*zt0[gr];
                a1 += zt1[gt]*zt1[gr];
            }
            v0[k] = a0; v1[k] = a1;
            const float w = (tt == rr2) ? 1.0f : 2.0f;
            ssql += w*(a0*a0 + a1*a1);
        }
        float ssq = ssql + __shfl_xor(ssql, 1);
        const float rn = __builtin_amdgcn_rsqf(fmaxf(ssq, 1e-24f));
        #pragma unroll
        for (int k = 0; k < 15; k++) {
            const int tt = PT[k], rr2 = PR[k];
            unsigned pkv = pk2(v0[k]*rn, v1[k]*rn);
            *(unsigned*)(&ssh[row*136 + tt*20 + rr2*4 + 2*sub]) = pkv;
            if (tt != rr2)
                *(unsigned*)(&ssh[row*136 + rr2*20 + tt*4 + 2*sub]) = pkv;
        }
        {
            const float* ep = edf + (size_t)e*16 + sub*8;
            f32x4 f0 = *(const f32x4*)ep, f1 = *(const f32x4*)(ep+4);
            int cb = row*136 + 100 + sub*8;
            *(unsigned*)(&ssh[cb+0]) = pk2(f0[0], f0[1]);
            *(unsigned*)(&ssh[cb+2]) = pk2(f0[2], f0[3]);
            *(unsigned*)(&ssh[cb+4]) = pk2(f1[0], f1[1]);
            *(unsigned*)(&ssh[cb+6]) = pk2(f1[2], f1[3]);
        }
        #pragma unroll
        for (int k = 0; k < 5; k++)
            *(unsigned*)(&ssh[row*136 + 116 + (sub*5 + k)*2]) = 0;
    }
    LDS_FENCE();

    // ---- GEMM phase: 2 A-tiles (32 edges) share every B-fragment load ----
    const int quad = lane >> 4;
    const int c15  = lane & 15;
    const int rA0  = wb + c15;
    const int rA1  = wb + 16 + c15;
    const short* sA0 = ssh + rA0*136 + quad*8;
    const short* sA1 = ssh + rA1*136 + quad*8;
    const f32x4 z4 = {0.f,0.f,0.f,0.f};

    // Layer 1
    f32x4 acc1[2][8];
    #pragma unroll
    for (int nt = 0; nt < 8; nt++) { acc1[0][nt] = z4; acc1[1][nt] = z4; }
    if (BF) {
        // K=128 over invar(100)+edf(16)+pad, B rows 256..383 ; zero-init acc
        const short* Bp = Wm1T + (size_t)c15*384 + 256 + quad*8;
        #pragma unroll
        for (int ks = 0; ks < 4; ks++) {
            s8b a0 = *(const s8b*)(sA0 + ks*32);
            s8b a1 = *(const s8b*)(sA1 + ks*32);
            #pragma unroll
            for (int nt = 0; nt < 8; nt++) {
                s8b b = *(const s8b*)(Bp + nt*(16*384) + ks*32);
                acc1[0][nt] = MFMA16(a0, b, acc1[0][nt]);
                acc1[1][nt] = MFMA16(a1, b, acc1[1][nt]);
            }
        }
        LDS_FENCE();
        // epilogue: + Yd[dst] (f32) + Ys[src] (bf16) + bias, silu, store act1
        float bias8[8];
        #pragma unroll
        for (int nt = 0; nt < 8; nt++) bias8[nt] = bm1f[nt*16 + c15];
        #pragma unroll
        for (int tl = 0; tl < 2; tl++)
            #pragma unroll
            for (int r = 0; r < 4; r++) {
                const int rw = wb + tl*16 + quad*4 + r;
                const float* yd = Ydf + (size_t)dsts[rw]*128 + c15*8;
                const short* ys = Ysb + (size_t)srcs[rw]*128 + c15*8;
                f32x4 y0 = *(const f32x4*)yd;
                f32x4 y1 = *(const f32x4*)(yd + 4);
                s8b yv = *(const s8b*)ys;
                #pragma unroll
                for (int nt = 0; nt < 8; nt++) {
                    float ydv = (nt < 4) ? y0[nt] : y1[nt-4];
                    float val = acc1[tl][nt][r] + ydv + bs2f(yv[nt]) + bias8[nt];
                    ssh[rw*136 + nt*16 + c15] = f2bs_fast(silu_f(val));
                }
            }
    } else {
        const short* Bp = Wm1T + (size_t)c15*384 + quad*8;
        const float* hd0 = h + (size_t)dsts[rA0]*128 + quad*8;
        const float* hs0 = h + (size_t)srcs[rA0]*128 + quad*8;
        const float* hd1 = h + (size_t)dsts[rA1]*128 + quad*8;
        const float* hs1 = h + (size_t)srcs[rA1]*128 + quad*8;
        #pragma unroll
        for (int ks = 0; ks < 12; ks++) {
            s8b a0, a1;
            if (ks < 4)      { a0 = load8f_bf(hd0 + ks*32);     a1 = load8f_bf(hd1 + ks*32); }
            else if (ks < 8) { a0 = load8f_bf(hs0 + (ks-4)*32); a1 = load8f_bf(hs1 + (ks-4)*32); }
            else             { a0 = *(const s8b*)(sA0 + (ks-8)*32); a1 = *(const s8b*)(sA1 + (ks-8)*32); }
            #pragma unroll
            for (int nt = 0; nt < 8; nt++) {
                s8b b = *(const s8b*)(Bp + nt*(16*384) + ks*32);
                acc1[0][nt] = MFMA16(a0, b, acc1[0][nt]);
                acc1[1][nt] = MFMA16(a1, b, acc1[1][nt]);
            }
        }
        LDS_FENCE();
        #pragma unroll
        for (int nt = 0; nt < 8; nt++) {
            const int col = nt*16 + c15;
            const float bias = bm1f[col];
            #pragma unroll
            for (int tl = 0; tl < 2; tl++)
                #pragma unroll
                for (int r = 0; r < 4; r++)
                    ssh[(wb + tl*16 + quad*4 + r)*136 + col] = f2bs_fast(silu_f(acc1[tl][nt][r] + bias));
        }
    }
    LDS_FENCE();

    // Layer 2: act1 @ Wm2 -> msg (LDS only)
    f32x4 acc2[2][8];
    #pragma unroll
    for (int nt = 0; nt < 8; nt++) { acc2[0][nt] = z4; acc2[1][nt] = z4; }
    {
        const short* Bp = Wm2T + (size_t)c15*128 + quad*8;
        #pragma unroll
        for (int ks = 0; ks < 4; ks++) {
            s8b a0 = *(const s8b*)(sA0 + ks*32);
            s8b a1 = *(const s8b*)(sA1 + ks*32);
            #pragma unroll
            for (int nt = 0; nt < 8; nt++) {
                s8b b = *(const s8b*)(Bp + nt*(16*128) + ks*32);
                acc2[0][nt] = MFMA16(a0, b, acc2[0][nt]);
                acc2[1][nt] = MFMA16(a1, b, acc2[1][nt]);
            }
        }
    }
    LDS_FENCE();
    #pragma unroll
    for (int nt = 0; nt < 8; nt++) {
        const int col = nt*16 + c15;
        const float bias = bm2[col];
        #pragma unroll
        for (int tl = 0; tl < 2; tl++)
            #pragma unroll
            for (int r = 0; r < 4; r++) {
                const int rw = wb + tl*16 + quad*4 + r;
                ssh[rw*136 + col] = f2bs_fast(silu_f(acc2[tl][nt][r] + bias));
            }
    }
    LDS_FENCE();

    // ---- macc segmented reduction, wave-private (own 32 sorted rows) ----
    {
        #pragma unroll
        for (int half = 0; half < 2; half++) {
            const int col = lane + half*64;
            float run = 0.f;
            int cur = dsts[wb];
            for (int r2 = wb; r2 < wb + EPW; r2++) {
                int d2 = dsts[r2];
                if (d2 != cur) {
                    atomicAdd(macc + (size_t)cur*128 + col, run);
                    run = 0.f; cur = d2;
                }
                run += bs2f(ssh[r2*136 + col]);
            }
            atomicAdd(macc + (size_t)cur*128 + col, run);
        }
    }

    // Layer 3: msg @ Wv1 -> act3
    f32x4 acc3[2][8];
    #pragma unroll
    for (int nt = 0; nt < 8; nt++) { acc3[0][nt] = z4; acc3[1][nt] = z4; }
    {
        const short* Bp = Wv1T + (size_t)c15*128 + quad*8;
        #pragma unroll
        for (int ks = 0; ks < 4; ks++) {
            s8b a0 = *(const s8b*)(sA0 + ks*32);
            s8b a1 = *(const s8b*)(sA1 + ks*32);
            #pragma unroll
            for (int nt = 0; nt < 8; nt++) {
                s8b b = *(const s8b*)(Bp + nt*(16*128) + ks*32);
                acc3[0][nt] = MFMA16(a0, b, acc3[0][nt]);
                acc3[1][nt] = MFMA16(a1, b, acc3[1][nt]);
            }
        }
    }
    LDS_FENCE();
    #pragma unroll
    for (int nt = 0; nt < 8; nt++) {
        const int col = nt*16 + c15;
        const float bias = bv1[col];
        #pragma unroll
        for (int tl = 0; tl < 2; tl++)
            #pragma unroll
            for (int r = 0; r < 4; r++)
                ssh[(wb + tl*16 + quad*4 + r)*136 + col] = f2bs_fast(silu_f(acc3[tl][nt][r] + bias));
    }
    LDS_FENCE();

    // Layer 4: act3 @ Wv2 -> basis[80]
    f32x4 acc4[2][5];
    #pragma unroll
    for (int nt = 0; nt < 5; nt++) { acc4[0][nt] = z4; acc4[1][nt] = z4; }
    {
        const short* Bp = Wv2T + (size_t)c15*128 + quad*8;
        #pragma unroll
        for (int ks = 0; ks < 4; ks++) {
            s8b a0 = *(const s8b*)(sA0 + ks*32);
            s8b a1 = *(const s8b*)(sA1 + ks*32);
            #pragma unroll
            for (int nt = 0; nt < 5; nt++) {
                s8b b = *(const s8b*)(Bp + nt*(16*128) + ks*32);
                acc4[0][nt] = MFMA16(a0, b, acc4[0][nt]);
                acc4[1][nt] = MFMA16(a1, b, acc4[1][nt]);
            }
        }
    }
    // act3 dead -> restage Z_ij from registers into ssh cols 0..59 (own rows)
    LDS_FENCE();
    {
        #pragma unroll
        for (int d2 = 0; d2 < 3; d2++) {
            #pragma unroll
            for (int t = 0; t < 4; t++)
                *(unsigned*)(&ssh[row*136 + d2*20 + t*4 + 2*sub]) = zp[d2*4 + t];
            *(unsigned*)(&ssh[row*136 + d2*20 + 16 + 2*sub]) = zp[12 + d2];
        }
    }
    LDS_FENCE();
    // contract with Z_ij ; stage Zagg (bf16) into ssh cols 64..111 (own rows)
    {
        const int hh = c15 & 3;                   // basis col = t*16 + (k*4+h); c15 = k*4+h
        float bs[5];
        #pragma unroll
        for (int t = 0; t < 5; t++) bs[t] = bv2[t*16 + c15];
        #pragma unroll
        for (int tl = 0; tl < 2; tl++)
            #pragma unroll
            for (int r = 0; r < 4; r++) {
                const int rw = wb + tl*16 + quad*4 + r;
                float bt[5];
                #pragma unroll
                for (int t = 0; t < 5; t++) bt[t] = acc4[tl][t][r] + bs[t];
                #pragma unroll
                for (int dd = 0; dd < 3; dd++) {
                    float s0 = 0.f;
                    #pragma unroll
                    for (int t = 0; t < 5; t++)
                        s0 += bs2f(ssh[rw*136 + dd*20 + t*4 + hh]) * bt[t];
                    ssh[rw*136 + 64 + dd*16 + c15] = f2bs_fast(s0);
                }
            }
    }
    LDS_FENCE();

    // ---- Zacc segmented reduction, wave-private (own 32 rows, 48 cols) ----
    {
        const int colz = lane;
        if (colz < 48) {
            float run = 0.f;
            int cur = dsts[wb];
            for (int r2 = wb; r2 < wb + EPW; r2++) {
                int d2 = dsts[r2];
                if (d2 != cur) {
                    atomicAdd(Zacc + (size_t)cur*48 + colz, run);
                    run = 0.f; cur = d2;
                }
                run += bs2f(ssh[r2*136 + 64 + colz]);
            }
            atomicAdd(Zacc + (size_t)cur*48 + colz, run);
        }
    }
}

// ---------------- node kernel ----------------
__global__ __launch_bounds__(256) void node_kernel(
    const float* __restrict__ h,
    const short* __restrict__ Ws1T, const float* __restrict__ bs1,
    const short* __restrict__ Ws2T, const float* __restrict__ bs2,
    const float* __restrict__ Zacc, const float* __restrict__ macc,
    const int* __restrict__ deg, float* __restrict__ out)
{
    __shared__ __align__(16) short ssh[64*136];   // m stage -> act1
    const int tid = threadIdx.x, lane = tid & 63, wave = tid >> 6;
    const int mb = wave*16;
    const int nbase = blockIdx.x * 64;

    // Z_out = Zacc / max(deg,1)
    for (int i = tid; i < 64*48; i += 256) {
        int nl = i / 48, c2 = i - nl*48;
        int nd = nbase + nl;
        if (nd < NND) {
            float ct = fmaxf((float)deg[nd], 1.0f);
            out[(size_t)nd*48 + c2] = Zacc[(size_t)nd*48 + c2] / ct;
        }
    }

    // stage m (bf16), wave-private rows
    {
        const int row = mb + (lane >> 2);
        const int sub = lane & 3;
        int nd = nbase + row; if (nd >= NND) nd = 0;
        const float* mr = macc + (size_t)nd*128 + sub*32;
        #pragma unroll
        for (int j = 0; j < 8; j++) {
            f32x4 v = *(const f32x4*)(mr + j*4);
            int cb = row*136 + sub*32 + j*4;
            *(unsigned*)(&ssh[cb+0]) = pk2(v[0], v[1]);
            *(unsigned*)(&ssh[cb+2]) = pk2(v[2], v[3]);
        }
    }
    LDS_FENCE();

    const int quad = lane >> 4, c15 = lane & 15;
    const int rA = mb + c15;
    int ndA = nbase + rA; if (ndA >= NND) ndA = 0;   // clamp; stores guarded
    const float* hA = h + (size_t)ndA*128 + quad*8;
    const short* sA = ssh + rA*136 + quad*8;
    const f32x4 z4 = {0.f,0.f,0.f,0.f};

    // GEMM1: [h | m] (K=256) @ Ws1
    f32x4 acc1[8];
    #pragma unroll
    for (int nt = 0; nt < 8; nt++) acc1[nt] = z4;
    {
        const short* Bp = Ws1T + (size_t)c15*256 + quad*8;
        #pragma unroll
        for (int ks = 0; ks < 8; ks++) {
            s8b a;
            if (ks < 4) a = load8f_bf(hA + ks*32);
            else        a = *(const s8b*)(sA + (ks-4)*32);
            #pragma unroll
            for (int nt = 0; nt < 8; nt++) {
                s8b b = *(const s8b*)(Bp + nt*(16*256) + ks*32);
                acc1[nt] = MFMA16(a, b, acc1[nt]);
            }
        }
    }
    LDS_FENCE();
    #pragma unroll
    for (int nt = 0; nt < 8; nt++) {
        const int col = nt*16 + c15;
        const float bias = bs1[col];
        #pragma unroll
        for (int r = 0; r < 4; r++)
            ssh[(mb + quad*4 + r)*136 + col] = f2bs_fast(silu_f(acc1[nt][r] + bias));
    }
    LDS_FENCE();

    // GEMM2: act @ Ws2 -> h_out
    f32x4 acc2[8];
    #pragma unroll
    for (int nt = 0; nt < 8; nt++) acc2[nt] = z4;
    {
        const short* Bp = Ws2T + (size_t)c15*128 + quad*8;
        #pragma unroll
        for (int ks = 0; ks < 4; ks++) {
            s8b a = *(const s8b*)(sA + ks*32);
            #pragma unroll
            for (int nt = 0; nt < 8; nt++) {
                s8b b = *(const s8b*)(Bp + nt*(16*128) + ks*32);
                acc2[nt] = MFMA16(a, b, acc2[nt]);
            }
        }
    }
    {
        float* oh = out + (size_t)NND*48;
        #pragma unroll
        for (int nt = 0; nt < 8; nt++) {
            const int col = nt*16 + c15;
            const float bias = bs2[col];
            #pragma unroll
            for (int r = 0; r < 4; r++) {
                const int rw = mb + quad*4 + r;
                const int nd = nbase + rw;
                if (nd < NND)
                    oh[(size_t)nd*128 + col] = acc2[nt][r] + bias;
            }
        }
    }
}

extern "C" void kernel_launch(void* const* d_in, const int* in_sizes, int n_in,
                              void* d_out, int out_size, void* d_ws, size_t ws_size,
                              hipStream_t stream)
{
    const float* Z   = (const float*)d_in[0];
    const float* h   = (const float*)d_in[1];
    const int*   ei  = (const int*)d_in[2];
    const float* edf = (const float*)d_in[3];
    const float* edv = (const float*)d_in[4];
    const float* We  = (const float*)d_in[6];
    const float* be  = (const float*)d_in[7];
    const float* Wm1 = (const float*)d_in[8];
    const float* bm1 = (const float*)d_in[9];
    const float* Wm2 = (const float*)d_in[10];
    const float* bm2 = (const float*)d_in[11];
    const float* Wv1 = (const float*)d_in[12];
    const float* bv1 = (const float*)d_in[13];
    const float* Wv2 = (const float*)d_in[14];
    const float* bv2 = (const float*)d_in[15];
    const float* Ws1 = (const float*)d_in[16];
    const float* bs1 = (const float*)d_in[17];
    const float* Ws2 = (const float*)d_in[18];
    const float* bs2 = (const float*)d_in[19];

    if (ws_size < WS_MIN) return;
    const bool bf = (ws_size >= WS_FULL);

    char* wsc = (char*)d_ws;
    short* wsb = (short*)d_ws;
    float* bm1f = (float*)(wsc + BM1F_BYTE);
    float* Zacc = (float*)(wsc + ACC_BYTE);
    float* macc = Zacc + ZACC_ELEMS;
    int*   deg  = (int*)(macc + MACC_ELEMS);
    int*   cursor = deg + NND;
    int*   perm   = cursor + NND;
    int*   part   = perm + NED;
    short* zbf    = (short*)(wsc + ZB_BYTE);
    float* Ydp    = (float*)(wsc + YD_BYTE);
    short* Ysb    = (short*)(wsc + YS_BYTE);

    zero_kernel<<<2048, 256, 0, stream>>>(Zacc, ACC_TOTAL);   // Zacc + macc + deg
    fold_kernel<<<192, 256, 0, stream>>>(We, be, Wm1, bm1, wsb + WM1T_OFF, bm1f);
    prep_kernel<<<360, 256, 0, stream>>>(Wm2, Wv1, Wv2, Ws1, Ws2, wsb);
    if (bf) {
        cvt_kernel<<<1024, 256, 0, stream>>>(Z, zbf, NND*48);
        y_kernel<<<(NND + 63)/64, 256, 0, stream>>>(h, wsb + WM1T_OFF, Ydp, Ysb);
    }
    hist_kernel<<<(NED + 255)/256, 256, 0, stream>>>(ei, deg);
    scan1_kernel<<<SCH, 256, 0, stream>>>(deg, part);
    scan2_kernel<<<1, 256, 0, stream>>>(part);
    scan3_kernel<<<SCH, 256, 0, stream>>>(deg, part, cursor);
    scatter_kernel<<<(NED + 255)/256, 256, 0, stream>>>(ei, cursor, perm);
    if (bf) {
        edge_kernel<1><<<NED/EPB, 256, 0, stream>>>(Z, h, zbf, Ydp, Ysb, ei, perm, edf, edv,
            wsb + WM1T_OFF, bm1f, wsb + WM2T_OFF, bm2, wsb + WV1T_OFF, bv1,
            wsb + WV2T_OFF, bv2, Zacc, macc);
    } else {
        edge_kernel<0><<<NED/EPB, 256, 0, stream>>>(Z, h, zbf, Ydp, Ysb, ei, perm, edf, edv,
            wsb + WM1T_OFF, bm1f, wsb + WM2T_OFF, bm2, wsb + WV1T_OFF, bv1,
            wsb + WV2T_OFF, bv2, Zacc, macc);
    }
    node_kernel<<<(NND + 63)/64, 256, 0, stream>>>(h, wsb + WS1T_OFF, bs1,
        wsb + WS2T_OFF, bs2, Zacc, macc, deg, (float*)d_out);
}

// Round 3
// 836.152 us; speedup vs baseline: 1.0614x; 1.0614x over previous
//
#include <hip/hip_runtime.h>
#include <hip/hip_bf16.h>

typedef __attribute__((ext_vector_type(8))) short s8b;     // 8 bf16 (4 VGPRs)
typedef __attribute__((ext_vector_type(4))) float f32x4;   // MFMA accumulator
typedef __attribute__((ext_vector_type(4))) unsigned u32x4;

#define NND 50000
#define NED 800000
#define EPB 128     // edges per block
#define EPW 32      // edges per wave
#define SCH 200     // scan chunks
#define SCS 250     // chunk size: 200*250 = 50000

// workspace layout (bf16-element offsets for weights, byte offsets for f32)
#define WM1T_OFF 0         // [128][384] folded+transposed Wm1'
#define WM2T_OFF 49152     // [128][128]
#define WV1T_OFF 65536     // [128][128]
#define WV2T_OFF 81920     // [80][128]
#define WS1T_OFF 92160     // [128][256]
#define WS2T_OFF 124928    // [128][128]
#define BM1F_BYTE 282624   // 128 f32 (folded bias)
#define ACC_BYTE  283136   // f32 accumulators start (16B aligned)
#define ZACC_ELEMS (NND*48)
#define MACC_ELEMS (NND*128)
#define ACC_TOTAL (ZACC_ELEMS + MACC_ELEMS + NND)   // Zacc + macc + deg (zeroed)
// ints after acc: cursor[NND], perm[NED], part[256]
#define WS_MIN  (ACC_BYTE + (size_t)(ACC_TOTAL + NND + NED + 256)*4)
// tier1 staging: Z bf16 + per-node L1 partials Yd (f32, frag) + Ys (bf16, frag)
#define ZB_BYTE  ((WS_MIN + 15) & ~(size_t)15)
#define YD_BYTE  (ZB_BYTE + (size_t)NND*48*2)
#define YS_BYTE  (YD_BYTE + (size_t)NND*128*4)
#define WS_BF1   (YS_BYTE + (size_t)NND*128*2)
// tier2 staging: dst-sorted edge data (src/dst int2, edv bf16x4, edf bf16x16)
#define SD_BYTE  ((WS_BF1 + 15) & ~(size_t)15)
#define EV_BYTE  (SD_BYTE + (size_t)NED*8)
#define EF_BYTE  (EV_BYTE + (size_t)NED*8)
#define WS_BF2   (EF_BYTE + (size_t)NED*32)

// accurate RNE cvt (prep only)
__device__ __forceinline__ short f2bs(float x){
    __hip_bfloat16 b = __float2bfloat16(x);
    return __builtin_bit_cast(short, b);
}
// fast cvt: round-half-up, 2 VALU ops (finite inputs only)
__device__ __forceinline__ short f2bs_fast(float x){
    unsigned u = __builtin_bit_cast(unsigned, x) + 0x8000u;
    return (short)(u >> 16);
}
// pack 2 floats -> 2 bf16 in one dword (lo=a, hi=b)
__device__ __forceinline__ unsigned pk2(float a, float b){
    unsigned ua = __builtin_bit_cast(unsigned, a) + 0x8000u;
    unsigned ub = __builtin_bit_cast(unsigned, b) + 0x8000u;
    return __builtin_amdgcn_perm(ub, ua, 0x07060302u);
}
// RNE pack (prep-side quality)
__device__ __forceinline__ unsigned pk2r(float a, float b){
    return ((unsigned)(unsigned short)f2bs(b) << 16) | (unsigned)(unsigned short)f2bs(a);
}
__device__ __forceinline__ float bs2f(short s){
    unsigned u = ((unsigned)(unsigned short)s) << 16;
    return __builtin_bit_cast(float, u);
}
__device__ __forceinline__ float upk_lo(unsigned u){
    return __builtin_bit_cast(float, u << 16);
}
__device__ __forceinline__ float upk_hi(unsigned u){
    return __builtin_bit_cast(float, u & 0xffff0000u);
}
__device__ __forceinline__ float silu_f(float x){
    float e = __expf(-x);
    return x * __builtin_amdgcn_rcpf(1.0f + e);
}
// load 8 consecutive f32 (16B-aligned) -> bf16 fragment
__device__ __forceinline__ s8b load8f_bf(const float* p){
    f32x4 a = *(const f32x4*)p;
    f32x4 b = *(const f32x4*)(p + 4);
    u32x4 r;
    r[0] = pk2(a[0], a[1]); r[1] = pk2(a[2], a[3]);
    r[2] = pk2(b[0], b[1]); r[3] = pk2(b[2], b[3]);
    return __builtin_bit_cast(s8b, r);
}

#define MFMA16(a,b,c) __builtin_amdgcn_mfma_f32_16x16x32_bf16((a),(b),(c),0,0,0)
#define LDS_FENCE() asm volatile("s_waitcnt lgkmcnt(0)" ::: "memory")

// ---------------- zero / cvt ----------------
__global__ __launch_bounds__(256) void zero_kernel(float* __restrict__ p, int n)
{
    int i = blockIdx.x*256 + threadIdx.x;
    int stride = gridDim.x*256;
    for (; i < n; i += stride) p[i] = 0.0f;
}
__global__ __launch_bounds__(256) void cvt_kernel(const float* __restrict__ src,
                                                  short* __restrict__ dst, int n)
{
    int i = blockIdx.x*256 + threadIdx.x;
    int stride = gridDim.x*256;
    for (; i < n; i += stride) dst[i] = f2bs(src[i]);
}

// ---------------- weight prep ----------------
__global__ __launch_bounds__(256) void fold_kernel(
    const float* __restrict__ We, const float* __restrict__ be,
    const float* __restrict__ Wm1, const float* __restrict__ bm1,
    short* __restrict__ Wm1T, float* __restrict__ bm1f)
{
    int idx = blockIdx.x*256 + threadIdx.x;
    if (idx >= 128*384) return;
    int n = idx / 384, k = idx - n*384;
    float v;
    if (k < 356) v = Wm1[(size_t)k*128 + n];
    else if (k < 372) {
        int j = k - 356; float s = 0.f;
        for (int c = 0; c < 128; c++)
            s += We[j*128 + c] * Wm1[(size_t)(356+c)*128 + n];
        v = s;
    } else v = 0.f;
    Wm1T[(size_t)n*384 + k] = f2bs(v);
    if (k == 0) {
        float s = bm1[n];
        for (int c = 0; c < 128; c++)
            s += be[c] * Wm1[(size_t)(356+c)*128 + n];
        bm1f[n] = s;
    }
}

__global__ __launch_bounds__(256) void prep_kernel(
    const float* __restrict__ Wm2, const float* __restrict__ Wv1,
    const float* __restrict__ Wv2, const float* __restrict__ Ws1,
    const float* __restrict__ Ws2, short* __restrict__ wsb)
{
    int i = blockIdx.x*256 + threadIdx.x;
    if (i < 16384) { int k=i>>7, n=i&127; wsb[WM2T_OFF + n*128 + k] = f2bs(Wm2[i]); return; }
    i -= 16384;
    if (i < 16384) { int k=i>>7, n=i&127; wsb[WV1T_OFF + n*128 + k] = f2bs(Wv1[i]); return; }
    i -= 16384;
    if (i < 10240) { int k=i/80, n=i-k*80; wsb[WV2T_OFF + n*128 + k] = f2bs(Wv2[i]); return; }
    i -= 10240;
    if (i < 32768) { int k=i>>7, n=i&127; wsb[WS1T_OFF + n*256 + k] = f2bs(Ws1[i]); return; }
    i -= 32768;
    if (i < 16384) { int k=i>>7, n=i&127; wsb[WS2T_OFF + n*128 + k] = f2bs(Ws2[i]); return; }
}

// ---------------- per-node L1 partials ----------------
// Yd = h @ Wm1[h_i] (f32, fragment layout [node][c15*8+nt] <-> col nt*16+c15)
// Ys = h @ Wm1[h_j] (bf16, same layout) -- src-side gather traffic halved
__global__ __launch_bounds__(256) void y_kernel(
    const float* __restrict__ h, const short* __restrict__ Wm1T,
    float* __restrict__ Yd, short* __restrict__ Ysb)
{
    const int tid = threadIdx.x, lane = tid & 63, wave = tid >> 6;
    const int quad = lane >> 4, c15 = lane & 15;
    const int nbase = blockIdx.x * 64 + wave * 16;
    int ndA = nbase + c15; if (ndA >= NND) ndA = NND - 1;   // clamp; stores guarded
    const float* hA = h + (size_t)ndA*128 + quad*8;
    const f32x4 z4 = {0.f,0.f,0.f,0.f};
    f32x4 ad[8], as_[8];
    #pragma unroll
    for (int nt = 0; nt < 8; nt++) { ad[nt] = z4; as_[nt] = z4; }
    const short* Bd = Wm1T + (size_t)c15*384 + quad*8;      // k 0..127  (h_i / dst)
    const short* Bs = Bd + 128;                             // k 128..255 (h_j / src)
    #pragma unroll
    for (int ks = 0; ks < 4; ks++) {
        s8b a = load8f_bf(hA + ks*32);
        #pragma unroll
        for (int nt = 0; nt < 8; nt++) {
            s8b bd = *(const s8b*)(Bd + nt*(16*384) + ks*32);
            s8b bs = *(const s8b*)(Bs + nt*(16*384) + ks*32);
            ad[nt]  = MFMA16(a, bd, ad[nt]);
            as_[nt] = MFMA16(a, bs, as_[nt]);
        }
    }
    #pragma unroll
    for (int r = 0; r < 4; r++) {
        const int nd = nbase + quad*4 + r;
        if (nd < NND) {
            f32x4 w0 = {ad[0][r], ad[1][r], ad[2][r], ad[3][r]};
            f32x4 w1 = {ad[4][r], ad[5][r], ad[6][r], ad[7][r]};
            *(f32x4*)(Yd + (size_t)nd*128 + c15*8)     = w0;
            *(f32x4*)(Yd + (size_t)nd*128 + c15*8 + 4) = w1;
            s8b yv;
            #pragma unroll
            for (int nt = 0; nt < 8; nt++) yv[nt] = f2bs(as_[nt][r]);
            *(s8b*)(Ysb + (size_t)nd*128 + c15*8) = yv;
        }
    }
}

// ---------------- counting sort by dst ----------------
__global__ __launch_bounds__(256) void hist_kernel(const int* __restrict__ ei, int* __restrict__ deg)
{
    int e = blockIdx.x*256 + threadIdx.x;
    if (e < NED) atomicAdd(&deg[ei[NED + e]], 1);
}

__global__ __launch_bounds__(256) void scan1_kernel(const int* __restrict__ deg, int* __restrict__ part)
{
    __shared__ int red[256];
    int b = blockIdx.x, t = threadIdx.x;
    red[t] = (t < SCS) ? deg[b*SCS + t] : 0;
    __syncthreads();
    for (int s = 128; s > 0; s >>= 1) {
        if (t < s) red[t] += red[t+s];
        __syncthreads();
    }
    if (t == 0) part[b] = red[0];
}
// parallel exclusive scan of the SCH partial sums
__global__ __launch_bounds__(256) void scan2_kernel(int* __restrict__ part)
{
    __shared__ int buf[256];
    int t = threadIdx.x;
    int v = (t < SCH) ? part[t] : 0;
    buf[t] = v;
    __syncthreads();
    for (int s = 1; s < 256; s <<= 1) {
        int add = (t >= s) ? buf[t-s] : 0;
        __syncthreads();
        buf[t] += add;
        __syncthreads();
    }
    if (t < SCH) part[t] = buf[t] - v;   // exclusive
}
__global__ __launch_bounds__(256) void scan3_kernel(const int* __restrict__ deg,
                                                    const int* __restrict__ part,
                                                    int* __restrict__ cursor)
{
    __shared__ int buf[256];
    int b = blockIdx.x, t = threadIdx.x;
    int v = (t < SCS) ? deg[b*SCS + t] : 0;
    buf[t] = v;
    __syncthreads();
    for (int s = 1; s < 256; s <<= 1) {
        int add = (t >= s) ? buf[t-s] : 0;
        __syncthreads();
        buf[t] += add;
        __syncthreads();
    }
    if (t < SCS) cursor[b*SCS + t] = part[b] + buf[t] - v;   // exclusive
}

// tier<2: classic scatter producing perm
__global__ __launch_bounds__(256) void scatter_kernel(const int* __restrict__ ei,
                                                      int* __restrict__ cursor,
                                                      int* __restrict__ perm)
{
    int e = blockIdx.x*256 + threadIdx.x;
    if (e < NED) {
        int d = ei[NED + e];
        int p = atomicAdd(&cursor[d], 1);
        perm[p] = e;
    }
}

// tier2: scatter + pre-permute edge data into dst-sorted order.
// Reads coalesced (ei, edv, edf); scattered WRITES are fire-and-forget
// (fully TLP-hidden at 8 waves/SIMD) -- removes 3 random-gather dependency
// levels from the occupancy-capped edge kernel.
__global__ __launch_bounds__(256) void scatter2_kernel(const int* __restrict__ ei,
    int* __restrict__ cursor, const float* __restrict__ edf, const float* __restrict__ edv,
    int2* __restrict__ sdS, short* __restrict__ evS, short* __restrict__ efS)
{
    int e = blockIdx.x*256 + threadIdx.x;
    if (e >= NED) return;
    int s = ei[e], d = ei[NED + e];
    int p = atomicAdd(&cursor[d], 1);
    sdS[p] = make_int2(s, d);
    float v0 = edv[(size_t)e*3+0], v1 = edv[(size_t)e*3+1], v2 = edv[(size_t)e*3+2];
    *(uint2*)(evS + (size_t)p*4) = make_uint2(pk2r(v0, v1), pk2r(v2, 0.f));
    const float* ep = edf + (size_t)e*16;
    f32x4 f0 = *(const f32x4*)ep,      f1 = *(const f32x4*)(ep+4);
    f32x4 f2 = *(const f32x4*)(ep+8),  f3 = *(const f32x4*)(ep+12);
    u32x4 a, b;
    a[0] = pk2r(f0[0], f0[1]); a[1] = pk2r(f0[2], f0[3]);
    a[2] = pk2r(f1[0], f1[1]); a[3] = pk2r(f1[2], f1[3]);
    b[0] = pk2r(f2[0], f2[1]); b[1] = pk2r(f2[2], f2[3]);
    b[2] = pk2r(f3[0], f3[1]); b[3] = pk2r(f3[2], f3[3]);
    *(u32x4*)(efS + (size_t)p*16)     = a;
    *(u32x4*)(efS + (size_t)p*16 + 8) = b;
}

// ---------------- edge kernel ----------------
// 128 dst-sorted edges/block, 4 waves x 32 edges (2 MFMA A-tiles).
// Everything wave-private: NO __syncthreads, only lgkm fences.
// BF=2: sorted-staged edge data (coalesced sdS/evS/efS), Zb bf16 gather,
//       L1 K=128 + Yd/Ys partials at epilogue.
// BF=1: as BF=2 but edge data via perm/ei/edf/edv gathers.
// BF=0: f32 everything, K=384 L1.
template<int BF>
__global__ __launch_bounds__(256, 4) void edge_kernel(
    const float* __restrict__ Z, const float* __restrict__ h,
    const short* __restrict__ Zb,
    const float* __restrict__ Ydf, const short* __restrict__ Ysb,
    const int* __restrict__ ei, const int* __restrict__ perm,
    const float* __restrict__ edf, const float* __restrict__ edv,
    const int2* __restrict__ sdS, const short* __restrict__ evS, const short* __restrict__ efS,
    const short* __restrict__ Wm1T, const float* __restrict__ bm1f,
    const short* __restrict__ Wm2T, const float* __restrict__ bm2,
    const short* __restrict__ Wv1T, const float* __restrict__ bv1,
    const short* __restrict__ Wv2T, const float* __restrict__ bv2,
    float* __restrict__ Zacc, float* __restrict__ macc)
{
    __shared__ __align__(16) short ssh[EPB*136];  // invar/edf -> act1 -> msg -> act3 -> Z+Zagg
    __shared__ int srcs[EPB], dsts[EPB];

    const int tid  = threadIdx.x;
    const int lane = tid & 63;
    const int wave = tid >> 6;
    const int wb   = wave * EPW;
    const int ebase= blockIdx.x * EPB;   // natural order: dst-sorted temporal locality

    const int row = wb + (lane >> 1);
    const int sub = lane & 1;          // h-parity: this lane owns h = 2*sub, 2*sub+1

    // ---- Phase A: indices + Z_ij diffs (packed bf16 pairs) + invariants ----
    unsigned zp[15];    // [g=d*4+t] for t<4 ; zp[12+d] = edv pair
    {
        const int p = ebase + row;
        int s, d;
        int e = 0;
        if (BF == 2) {
            int2 sd = sdS[p];
            s = sd.x; d = sd.y;
        } else {
            e = perm[p];
            s = ei[e]; d = ei[NED + e];
        }
        if (sub == 0) { srcs[row] = s; dsts[row] = d; }
        unsigned pA[6], pB[6], rc[6];
        if (BF >= 1) {
            const s8b zd0 = *(const s8b*)(Zb + (size_t)d*48 + sub*24);
            const s8b zd1 = *(const s8b*)(Zb + (size_t)d*48 + sub*24 + 8);
            const s8b zd2 = *(const s8b*)(Zb + (size_t)d*48 + sub*24 + 16);
            const s8b zs0 = *(const s8b*)(Zb + (size_t)s*48 + sub*24);
            const s8b zs1 = *(const s8b*)(Zb + (size_t)s*48 + sub*24 + 8);
            const s8b zs2 = *(const s8b*)(Zb + (size_t)s*48 + sub*24 + 16);
            u32x4 ud01 = __builtin_bit_cast(u32x4, zd0);
            u32x4 ud23 = __builtin_bit_cast(u32x4, zd1);
            u32x4 ud45 = __builtin_bit_cast(u32x4, zd2);
            u32x4 us01 = __builtin_bit_cast(u32x4, zs0);
            u32x4 us23 = __builtin_bit_cast(u32x4, zs1);
            u32x4 us45 = __builtin_bit_cast(u32x4, zs2);
            unsigned ud[12], us[12];
            #pragma unroll
            for (int j = 0; j < 4; j++) {
                ud[j] = ud01[j]; ud[4+j] = ud23[j]; ud[8+j] = ud45[j];
                us[j] = us01[j]; us[4+j] = us23[j]; us[8+j] = us45[j];
            }
            #pragma unroll
            for (int q = 0; q < 6; q++) {
                float l0 = upk_lo(ud[2*q])   - upk_lo(us[2*q]);
                float h0 = upk_hi(ud[2*q])   - upk_hi(us[2*q]);
                float l1 = upk_lo(ud[2*q+1]) - upk_lo(us[2*q+1]);
                float h1 = upk_hi(ud[2*q+1]) - upk_hi(us[2*q+1]);
                pA[q] = pk2(l0, h0);
                pB[q] = pk2(l1, h1);
            }
        } else {
            const float* Zs = Z + (size_t)s*48 + sub*24;
            const float* Zd = Z + (size_t)d*48 + sub*24;
            float dv[24];
            #pragma unroll
            for (int q = 0; q < 6; q++) {
                f32x4 a = *(const f32x4*)(Zd + q*4);
                f32x4 b = *(const f32x4*)(Zs + q*4);
                dv[q*4+0] = a[0]-b[0]; dv[q*4+1] = a[1]-b[1];
                dv[q*4+2] = a[2]-b[2]; dv[q*4+3] = a[3]-b[3];
            }
            #pragma unroll
            for (int q = 0; q < 6; q++) {
                pA[q] = pk2(dv[q*4+0], dv[q*4+1]);
                pB[q] = pk2(dv[q*4+2], dv[q*4+3]);
            }
        }
        #pragma unroll
        for (int q = 0; q < 6; q++)
            rc[q] = (unsigned)__shfl_xor((int)(sub ? pA[q] : pB[q]), 1);
        #pragma unroll
        for (int i = 0; i < 6; i++) zp[i]   = sub ? rc[i] : pA[i];
        #pragma unroll
        for (int i = 0; i < 6; i++) zp[6+i] = sub ? pB[i] : rc[i];
        if (BF == 2) {
            uint2 ev = *(const uint2*)(evS + (size_t)p*4);
            float e0 = upk_lo(ev.x), e1 = upk_hi(ev.x), e2 = upk_lo(ev.y);
            zp[12] = pk2(e0,e0); zp[13] = pk2(e1,e1); zp[14] = pk2(e2,e2);
        } else {
            float e0 = edv[(size_t)e*3+0], e1 = edv[(size_t)e*3+1], e2 = edv[(size_t)e*3+2];
            zp[12] = pk2(e0,e0); zp[13] = pk2(e1,e1); zp[14] = pk2(e2,e2);
        }

        // invariants (register-local Gram, h-diagonal)
        float zt0[15], zt1[15];
        #pragma unroll
        for (int i = 0; i < 15; i++) { zt0[i] = upk_lo(zp[i]); zt1[i] = upk_hi(zp[i]); }
        const int PT[15] = {0,0,0,0,0,1,1,1,1,2,2,2,3,3,4};
        const int PR[15] = {0,1,2,3,4,1,2,3,4,2,3,4,3,4,4};
        float v0[15], v1[15];
        float ssql = 0.f;
        #pragma unroll
        for (int k = 0; k < 15; k++) {
            const int tt = PT[k], rr2 = PR[k];
            float a0 = 0.f, a1 = 0.f;
            #pragma unroll
            for (int d2 = 0; d2 < 3; d2++) {
                const int gt = (tt < 4) ? d2*4 + tt : 12 + d2;
                const int gr = (rr2 < 4) ? d2*4 + rr2 : 12 + d2;
                a0 += zt0[gt]*zt0[gr];
                a1 += zt1[gt]*zt1[gr];
            }
            v0[k] = a0; v1[k] = a1;
            const float w = (tt == rr2) ? 1.0f : 2.0f;
            ssql += w*(a0*a0 + a1*a1);
        }
        float ssq = ssql + __shfl_xor(ssql, 1);
        const float rn = __builtin_amdgcn_rsqf(fmaxf(ssq, 1e-24f));
        #pragma unroll
        for (int k = 0; k < 15; k++) {
            const int tt = PT[k], rr2 = PR[k];
            unsigned pkv = pk2(v0[k]*rn, v1[k]*rn);
            *(unsigned*)(&ssh[row*136 + tt*20 + rr2*4 + 2*sub]) = pkv;
            if (tt != rr2)
                *(unsigned*)(&ssh[row*136 + rr2*20 + tt*4 + 2*sub]) = pkv;
        }
        if (BF == 2) {
            s8b ef = *(const s8b*)(efS + (size_t)p*16 + sub*8);
            u32x4 eu = __builtin_bit_cast(u32x4, ef);
            int cb = row*136 + 100 + sub*8;
            *(unsigned*)(&ssh[cb+0]) = eu[0];
            *(unsigned*)(&ssh[cb+2]) = eu[1];
            *(unsigned*)(&ssh[cb+4]) = eu[2];
            *(unsigned*)(&ssh[cb+6]) = eu[3];
        } else {
            const float* ep = edf + (size_t)e*16 + sub*8;
            f32x4 f0 = *(const f32x4*)ep, f1 = *(const f32x4*)(ep+4);
            int cb = row*136 + 100 + sub*8;
            *(unsigned*)(&ssh[cb+0]) = pk2(f0[0], f0[1]);
            *(unsigned*)(&ssh[cb+2]) = pk2(f0[2], f0[3]);
            *(unsigned*)(&ssh[cb+4]) = pk2(f1[0], f1[1]);
            *(unsigned*)(&ssh[cb+6]) = pk2(f1[2], f1[3]);
        }
        #pragma unroll
        for (int k = 0; k < 5; k++)
            *(unsigned*)(&ssh[row*136 + 116 + (sub*5 + k)*2]) = 0;
    }
    LDS_FENCE();

    // ---- GEMM phase: 2 A-tiles (32 edges) share every B-fragment load ----
    const int quad = lane >> 4;
    const int c15  = lane & 15;
    const int rA0  = wb + c15;
    const int rA1  = wb + 16 + c15;
    const short* sA0 = ssh + rA0*136 + quad*8;
    const short* sA1 = ssh + rA1*136 + quad*8;
    const f32x4 z4 = {0.f,0.f,0.f,0.f};

    // Layer 1
    f32x4 acc1[2][8];
    #pragma unroll
    for (int nt = 0; nt < 8; nt++) { acc1[0][nt] = z4; acc1[1][nt] = z4; }
    if (BF >= 1) {
        // K=128 over invar(100)+edf(16)+pad, B rows 256..383 ; zero-init acc
        const short* Bp = Wm1T + (size_t)c15*384 + 256 + quad*8;
        #pragma unroll
        for (int ks = 0; ks < 4; ks++) {
            s8b a0 = *(const s8b*)(sA0 + ks*32);
            s8b a1 = *(const s8b*)(sA1 + ks*32);
            #pragma unroll
            for (int nt = 0; nt < 8; nt++) {
                s8b b = *(const s8b*)(Bp + nt*(16*384) + ks*32);
                acc1[0][nt] = MFMA16(a0, b, acc1[0][nt]);
                acc1[1][nt] = MFMA16(a1, b, acc1[1][nt]);
            }
        }
        LDS_FENCE();
        // epilogue: + Yd[dst] (f32) + Ys[src] (bf16) + bias, silu, store act1
        float bias8[8];
        #pragma unroll
        for (int nt = 0; nt < 8; nt++) bias8[nt] = bm1f[nt*16 + c15];
        #pragma unroll
        for (int tl = 0; tl < 2; tl++)
            #pragma unroll
            for (int r = 0; r < 4; r++) {
                const int rw = wb + tl*16 + quad*4 + r;
                const float* yd = Ydf + (size_t)dsts[rw]*128 + c15*8;
                const short* ys = Ysb + (size_t)srcs[rw]*128 + c15*8;
                f32x4 y0 = *(const f32x4*)yd;
                f32x4 y1 = *(const f32x4*)(yd + 4);
                s8b yv = *(const s8b*)ys;
                #pragma unroll
                for (int nt = 0; nt < 8; nt++) {
                    float ydv = (nt < 4) ? y0[nt] : y1[nt-4];
                    float val = acc1[tl][nt][r] + ydv + bs2f(yv[nt]) + bias8[nt];
                    ssh[rw*136 + nt*16 + c15] = f2bs_fast(silu_f(val));
                }
            }
    } else {
        const short* Bp = Wm1T + (size_t)c15*384 + quad*8;
        const float* hd0 = h + (size_t)dsts[rA0]*128 + quad*8;
        const float* hs0 = h + (size_t)srcs[rA0]*128 + quad*8;
        const float* hd1 = h + (size_t)dsts[rA1]*128 + quad*8;
        const float* hs1 = h + (size_t)srcs[rA1]*128 + quad*8;
        #pragma unroll
        for (int ks = 0; ks < 12; ks++) {
            s8b a0, a1;
            if (ks < 4)      { a0 = load8f_bf(hd0 + ks*32);     a1 = load8f_bf(hd1 + ks*32); }
            else if (ks < 8) { a0 = load8f_bf(hs0 + (ks-4)*32); a1 = load8f_bf(hs1 + (ks-4)*32); }
            else             { a0 = *(const s8b*)(sA0 + (ks-8)*32); a1 = *(const s8b*)(sA1 + (ks-8)*32); }
            #pragma unroll
            for (int nt = 0; nt < 8; nt++) {
                s8b b = *(const s8b*)(Bp + nt*(16*384) + ks*32);
                acc1[0][nt] = MFMA16(a0, b, acc1[0][nt]);
                acc1[1][nt] = MFMA16(a1, b, acc1[1][nt]);
            }
        }
        LDS_FENCE();
        #pragma unroll
        for (int nt = 0; nt < 8; nt++) {
            const int col = nt*16 + c15;
            const float bias = bm1f[col];
            #pragma unroll
            for (int tl = 0; tl < 2; tl++)
                #pragma unroll
                for (int r = 0; r < 4; r++)
                    ssh[(wb + tl*16 + quad*4 + r)*136 + col] = f2bs_fast(silu_f(acc1[tl][nt][r] + bias));
        }
    }
    LDS_FENCE();

    // Layer 2: act1 @ Wm2 -> msg (LDS only)
    f32x4 acc2[2][8];
    #pragma unroll
    for (int nt = 0; nt < 8; nt++) { acc2[0][nt] = z4; acc2[1][nt] = z4; }
    {
        const short* Bp = Wm2T + (size_t)c15*128 + quad*8;
        #pragma unroll
        for (int ks = 0; ks < 4; ks++) {
            s8b a0 = *(const s8b*)(sA0 + ks*32);
            s8b a1 = *(const s8b*)(sA1 + ks*32);
            #pragma unroll
            for (int nt = 0; nt < 8; nt++) {
                s8b b = *(const s8b*)(Bp + nt*(16*128) + ks*32);
                acc2[0][nt] = MFMA16(a0, b, acc2[0][nt]);
                acc2[1][nt] = MFMA16(a1, b, acc2[1][nt]);
            }
        }
    }
    LDS_FENCE();
    #pragma unroll
    for (int nt = 0; nt < 8; nt++) {
        const int col = nt*16 + c15;
        const float bias = bm2[col];
        #pragma unroll
        for (int tl = 0; tl < 2; tl++)
            #pragma unroll
            for (int r = 0; r < 4; r++) {
                const int rw = wb + tl*16 + quad*4 + r;
                ssh[rw*136 + col] = f2bs_fast(silu_f(acc2[tl][nt][r] + bias));
            }
    }
    LDS_FENCE();

    // ---- macc segmented reduction, wave-private (own 32 sorted rows) ----
    {
        #pragma unroll
        for (int half = 0; half < 2; half++) {
            const int col = lane + half*64;
            float run = 0.f;
            int cur = dsts[wb];
            for (int r2 = wb; r2 < wb + EPW; r2++) {
                int d2 = dsts[r2];
                if (d2 != cur) {
                    atomicAdd(macc + (size_t)cur*128 + col, run);
                    run = 0.f; cur = d2;
                }
                run += bs2f(ssh[r2*136 + col]);
            }
            atomicAdd(macc + (size_t)cur*128 + col, run);
        }
    }

    // Layer 3: msg @ Wv1 -> act3
    f32x4 acc3[2][8];
    #pragma unroll
    for (int nt = 0; nt < 8; nt++) { acc3[0][nt] = z4; acc3[1][nt] = z4; }
    {
        const short* Bp = Wv1T + (size_t)c15*128 + quad*8;
        #pragma unroll
        for (int ks = 0; ks < 4; ks++) {
            s8b a0 = *(const s8b*)(sA0 + ks*32);
            s8b a1 = *(const s8b*)(sA1 + ks*32);
            #pragma unroll
            for (int nt = 0; nt < 8; nt++) {
                s8b b = *(const s8b*)(Bp + nt*(16*128) + ks*32);
                acc3[0][nt] = MFMA16(a0, b, acc3[0][nt]);
                acc3[1][nt] = MFMA16(a1, b, acc3[1][nt]);
            }
        }
    }
    LDS_FENCE();
    #pragma unroll
    for (int nt = 0; nt < 8; nt++) {
        const int col = nt*16 + c15;
        const float bias = bv1[col];
        #pragma unroll
        for (int tl = 0; tl < 2; tl++)
            #pragma unroll
            for (int r = 0; r < 4; r++)
                ssh[(wb + tl*16 + quad*4 + r)*136 + col] = f2bs_fast(silu_f(acc3[tl][nt][r] + bias));
    }
    LDS_FENCE();

    // Layer 4: act3 @ Wv2 -> basis[80]
    f32x4 acc4[2][5];
    #pragma unroll
    for (int nt = 0; nt < 5; nt++) { acc4[0][nt] = z4; acc4[1][nt] = z4; }
    {
        const short* Bp = Wv2T + (size_t)c15*128 + quad*8;
        #pragma unroll
        for (int ks = 0; ks < 4; ks++) {
            s8b a0 = *(const s8b*)(sA0 + ks*32);
            s8b a1 = *(const s8b*)(sA1 + ks*32);
            #pragma unroll
            for (int nt = 0; nt < 5; nt++) {
                s8b b = *(const s8b*)(Bp + nt*(16*128) + ks*32);
                acc4[0][nt] = MFMA16(a0, b, acc4[0][nt]);
                acc4[1][nt] = MFMA16(a1, b, acc4[1][nt]);
            }
        }
    }
    // act3 dead -> restage Z_ij from registers into ssh cols 0..59 (own rows)
    LDS_FENCE();
    {
        #pragma unroll
        for (int d2 = 0; d2 < 3; d2++) {
            #pragma unroll
            for (int t = 0; t < 4; t++)
                *(unsigned*)(&ssh[row*136 + d2*20 + t*4 + 2*sub]) = zp[d2*4 + t];
            *(unsigned*)(&ssh[row*136 + d2*20 + 16 + 2*sub]) = zp[12 + d2];
        }
    }
    LDS_FENCE();
    // contract with Z_ij ; stage Zagg (bf16) into ssh cols 64..111 (own rows)
    {
        const int hh = c15 & 3;                   // basis col = t*16 + (k*4+h); c15 = k*4+h
        float bs[5];
        #pragma unroll
        for (int t = 0; t < 5; t++) bs[t] = bv2[t*16 + c15];
        #pragma unroll
        for (int tl = 0; tl < 2; tl++)
            #pragma unroll
            for (int r = 0; r < 4; r++) {
                const int rw = wb + tl*16 + quad*4 + r;
                float bt[5];
                #pragma unroll
                for (int t = 0; t < 5; t++) bt[t] = acc4[tl][t][r] + bs[t];
                #pragma unroll
                for (int dd = 0; dd < 3; dd++) {
                    float s0 = 0.f;
                    #pragma unroll
                    for (int t = 0; t < 5; t++)
                        s0 += bs2f(ssh[rw*136 + dd*20 + t*4 + hh]) * bt[t];
                    ssh[rw*136 + 64 + dd*16 + c15] = f2bs_fast(s0);
                }
            }
    }
    LDS_FENCE();

    // ---- Zacc segmented reduction, wave-private (own 32 rows, 48 cols) ----
    {
        const int colz = lane;
        if (colz < 48) {
            float run = 0.f;
            int cur = dsts[wb];
            for (int r2 = wb; r2 < wb + EPW; r2++) {
                int d2 = dsts[r2];
                if (d2 != cur) {
                    atomicAdd(Zacc + (size_t)cur*48 + colz, run);
                    run = 0.f; cur = d2;
                }
                run += bs2f(ssh[r2*136 + 64 + colz]);
            }
            atomicAdd(Zacc + (size_t)cur*48 + colz, run);
        }
    }
}

// ---------------- node kernel ----------------
__global__ __launch_bounds__(256) void node_kernel(
    const float* __restrict__ h,
    const short* __restrict__ Ws1T, const float* __restrict__ bs1,
    const short* __restrict__ Ws2T, const float* __restrict__ bs2,
    const float* __restrict__ Zacc, const float* __restrict__ macc,
    const int* __restrict__ deg, float* __restrict__ out)
{
    __shared__ __align__(16) short ssh[64*136];   // m stage -> act1
    const int tid = threadIdx.x, lane = tid & 63, wave = tid >> 6;
    const int mb = wave*16;
    const int nbase = blockIdx.x * 64;

    // Z_out = Zacc / max(deg,1)
    for (int i = tid; i < 64*48; i += 256) {
        int nl = i / 48, c2 = i - nl*48;
        int nd = nbase + nl;
        if (nd < NND) {
            float ct = fmaxf((float)deg[nd], 1.0f);
            out[(size_t)nd*48 + c2] = Zacc[(size_t)nd*48 + c2] / ct;
        }
    }

    // stage m (bf16), wave-private rows
    {
        const int row = mb + (lane >> 2);
        const int sub = lane & 3;
        int nd = nbase + row; if (nd >= NND) nd = 0;
        const float* mr = macc + (size_t)nd*128 + sub*32;
        #pragma unroll
        for (int j = 0; j < 8; j++) {
            f32x4 v = *(const f32x4*)(mr + j*4);
            int cb = row*136 + sub*32 + j*4;
            *(unsigned*)(&ssh[cb+0]) = pk2(v[0], v[1]);
            *(unsigned*)(&ssh[cb+2]) = pk2(v[2], v[3]);
        }
    }
    LDS_FENCE();

    const int quad = lane >> 4, c15 = lane & 15;
    const int rA = mb + c15;
    int ndA = nbase + rA; if (ndA >= NND) ndA = 0;   // clamp; stores guarded
    const float* hA = h + (size_t)ndA*128 + quad*8;
    const short* sA = ssh + rA*136 + quad*8;
    const f32x4 z4 = {0.f,0.f,0.f,0.f};

    // GEMM1: [h | m] (K=256) @ Ws1
    f32x4 acc1[8];
    #pragma unroll
    for (int nt = 0; nt < 8; nt++) acc1[nt] = z4;
    {
        const short* Bp = Ws1T + (size_t)c15*256 + quad*8;
        #pragma unroll
        for (int ks = 0; ks < 8; ks++) {
            s8b a;
            if (ks < 4) a = load8f_bf(hA + ks*32);
            else        a = *(const s8b*)(sA + (ks-4)*32);
            #pragma unroll
            for (int nt = 0; nt < 8; nt++) {
                s8b b = *(const s8b*)(Bp + nt*(16*256) + ks*32);
                acc1[nt] = MFMA16(a, b, acc1[nt]);
            }
        }
    }
    LDS_FENCE();
    #pragma unroll
    for (int nt = 0; nt < 8; nt++) {
        const int col = nt*16 + c15;
        const float bias = bs1[col];
        #pragma unroll
        for (int r = 0; r < 4; r++)
            ssh[(mb + quad*4 + r)*136 + col] = f2bs_fast(silu_f(acc1[nt][r] + bias));
    }
    LDS_FENCE();

    // GEMM2: act @ Ws2 -> h_out
    f32x4 acc2[8];
    #pragma unroll
    for (int nt = 0; nt < 8; nt++) acc2[nt] = z4;
    {
        const short* Bp = Ws2T + (size_t)c15*128 + quad*8;
        #pragma unroll
        for (int ks = 0; ks < 4; ks++) {
            s8b a = *(const s8b*)(sA + ks*32);
            #pragma unroll
            for (int nt = 0; nt < 8; nt++) {
                s8b b = *(const s8b*)(Bp + nt*(16*128) + ks*32);
                acc2[nt] = MFMA16(a, b, acc2[nt]);
            }
        }
    }
    {
        float* oh = out + (size_t)NND*48;
        #pragma unroll
        for (int nt = 0; nt < 8; nt++) {
            const int col = nt*16 + c15;
            const float bias = bs2[col];
            #pragma unroll
            for (int r = 0; r < 4; r++) {
                const int rw = mb + quad*4 + r;
                const int nd = nbase + rw;
                if (nd < NND)
                    oh[(size_t)nd*128 + col] = acc2[nt][r] + bias;
            }
        }
    }
}

extern "C" void kernel_launch(void* const* d_in, const int* in_sizes, int n_in,
                              void* d_out, int out_size, void* d_ws, size_t ws_size,
                              hipStream_t stream)
{
    const float* Z   = (const float*)d_in[0];
    const float* h   = (const float*)d_in[1];
    const int*   ei  = (const int*)d_in[2];
    const float* edf = (const float*)d_in[3];
    const float* edv = (const float*)d_in[4];
    const float* We  = (const float*)d_in[6];
    const float* be  = (const float*)d_in[7];
    const float* Wm1 = (const float*)d_in[8];
    const float* bm1 = (const float*)d_in[9];
    const float* Wm2 = (const float*)d_in[10];
    const float* bm2 = (const float*)d_in[11];
    const float* Wv1 = (const float*)d_in[12];
    const float* bv1 = (const float*)d_in[13];
    const float* Wv2 = (const float*)d_in[14];
    const float* bv2 = (const float*)d_in[15];
    const float* Ws1 = (const float*)d_in[16];
    const float* bs1 = (const float*)d_in[17];
    const float* Ws2 = (const float*)d_in[18];
    const float* bs2 = (const float*)d_in[19];

    if (ws_size < WS_MIN) return;
    const int tier = (ws_size >= WS_BF2) ? 2 : (ws_size >= WS_BF1) ? 1 : 0;

    char* wsc = (char*)d_ws;
    short* wsb = (short*)d_ws;
    float* bm1f = (float*)(wsc + BM1F_BYTE);
    float* Zacc = (float*)(wsc + ACC_BYTE);
    float* macc = Zacc + ZACC_ELEMS;
    int*   deg  = (int*)(macc + MACC_ELEMS);
    int*   cursor = deg + NND;
    int*   perm   = cursor + NND;
    int*   part   = perm + NED;
    short* zbf    = (short*)(wsc + ZB_BYTE);
    float* Ydp    = (float*)(wsc + YD_BYTE);
    short* Ysb    = (short*)(wsc + YS_BYTE);
    int2*  sdS    = (int2*)(wsc + SD_BYTE);
    short* evS    = (short*)(wsc + EV_BYTE);
    short* efS    = (short*)(wsc + EF_BYTE);

    zero_kernel<<<2048, 256, 0, stream>>>(Zacc, ACC_TOTAL);   // Zacc + macc + deg
    fold_kernel<<<192, 256, 0, stream>>>(We, be, Wm1, bm1, wsb + WM1T_OFF, bm1f);
    prep_kernel<<<360, 256, 0, stream>>>(Wm2, Wv1, Wv2, Ws1, Ws2, wsb);
    if (tier >= 1) {
        cvt_kernel<<<1024, 256, 0, stream>>>(Z, zbf, NND*48);
        y_kernel<<<(NND + 63)/64, 256, 0, stream>>>(h, wsb + WM1T_OFF, Ydp, Ysb);
    }
    hist_kernel<<<(NED + 255)/256, 256, 0, stream>>>(ei, deg);
    scan1_kernel<<<SCH, 256, 0, stream>>>(deg, part);
    scan2_kernel<<<1, 256, 0, stream>>>(part);
    scan3_kernel<<<SCH, 256, 0, stream>>>(deg, part, cursor);
    if (tier == 2) {
        scatter2_kernel<<<(NED + 255)/256, 256, 0, stream>>>(ei, cursor, edf, edv,
            sdS, evS, efS);
        edge_kernel<2><<<NED/EPB, 256, 0, stream>>>(Z, h, zbf, Ydp, Ysb, ei, perm, edf, edv,
            sdS, evS, efS,
            wsb + WM1T_OFF, bm1f, wsb + WM2T_OFF, bm2, wsb + WV1T_OFF, bv1,
            wsb + WV2T_OFF, bv2, Zacc, macc);
    } else {
        scatter_kernel<<<(NED + 255)/256, 256, 0, stream>>>(ei, cursor, perm);
        if (tier == 1) {
            edge_kernel<1><<<NED/EPB, 256, 0, stream>>>(Z, h, zbf, Ydp, Ysb, ei, perm, edf, edv,
                sdS, evS, efS,
                wsb + WM1T_OFF, bm1f, wsb + WM2T_OFF, bm2, wsb + WV1T_OFF, bv1,
                wsb + WV2T_OFF, bv2, Zacc, macc);
        } else {
            edge_kernel<0><<<NED/EPB, 256, 0, stream>>>(Z, h, zbf, Ydp, Ysb, ei, perm, edf, edv,
                sdS, evS, efS,
                wsb + WM1T_OFF, bm1f, wsb + WM2T_OFF, bm2, wsb + WV1T_OFF, bv1,
                wsb + WV2T_OFF, bv2, Zacc, macc);
        }
    }
    node_kernel<<<(NND + 63)/64, 256, 0, stream>>>(h, wsb + WS1T_OFF, bs1,
        wsb + WS2T_OFF, bs2, Zacc, macc, deg, (float*)d_out);
}